// Round 2
// baseline (48.182 us; speedup 1.0000x reference)
//
#include <hip/hip_runtime.h>

// ClusteringLayer: q[n,k] = normalize_k( 1 / (1 + ||x_n - c_k||^2) )
// x: [65536,256] fp32, clusters: [256,256] fp32, out: [65536,256] fp32.
// R1: latency-bound fix. 32x32x16 MFMA, 1 wave = 32 rows x 256 cols,
// no LDS, no barriers, 2-deep global->reg ping-pong on A and B.

typedef _Float16 f16x8  __attribute__((ext_vector_type(8)));
typedef float    f32x4  __attribute__((ext_vector_type(4)));
typedef float    f32x16 __attribute__((ext_vector_type(16)));

#define DIM    256
#define NCLUST 256

// ---------------------------------------------------------------------------
// Pre-kernel: blocks 0..127  -> clusters fp32 -> f16 32x32-MFMA B-fragment order
//             blocks 128..383 -> c2[j] = sum_d clusters[j][d]^2
// B-fragment order: f16x8 index ((s*8 + t)*64 + lane) holds
// B[col = t*32 + (lane&31)][k = s*16 + (lane>>5)*8 + v], v = 0..7.
// (A uses the same (group,v)->k map, so any HW k-permutation cancels.)
// ---------------------------------------------------------------------------
__global__ __launch_bounds__(64) void pre_kernel(const float* __restrict__ clusters,
                                                 _Float16* __restrict__ bfrag,
                                                 float* __restrict__ c2) {
    int b = blockIdx.x;
    int l = threadIdx.x;  // 64 threads
    if (b < 128) {
        int s   = b >> 3;             // 0..15 (K step)
        int t   = b & 7;              // 0..7  (col tile)
        int col = t * 32 + (l & 31);
        int k0  = s * 16 + (l >> 5) * 8;
        const f32x4* p = reinterpret_cast<const f32x4*>(clusters + col * DIM + k0);
        f32x4 a = p[0];
        f32x4 c = p[1];
        f16x8 h;
        h[0] = (_Float16)a[0]; h[1] = (_Float16)a[1];
        h[2] = (_Float16)a[2]; h[3] = (_Float16)a[3];
        h[4] = (_Float16)c[0]; h[5] = (_Float16)c[1];
        h[6] = (_Float16)c[2]; h[7] = (_Float16)c[3];
        reinterpret_cast<f16x8*>(bfrag)[b * 64 + l] = h;
    } else {
        int j = b - 128;
        const f32x4* p = reinterpret_cast<const f32x4*>(clusters + j * DIM);
        f32x4 v = p[l];
        float s = v[0] * v[0] + v[1] * v[1] + v[2] * v[2] + v[3] * v[3];
#pragma unroll
        for (int m = 32; m >= 1; m >>= 1) s += __shfl_xor(s, m, 64);
        if (l == 0) c2[j] = s;
    }
}

// ---------------------------------------------------------------------------
// Main kernel: 2048 blocks x 64 threads (1 wave). Wave owns rows
// [blockIdx*32, +32) x all 256 cluster columns: 8 tiles of
// mfma_f32_32x32x16_f16, K=256 in 16 steps, 2-deep software pipeline.
// ---------------------------------------------------------------------------
__global__ __launch_bounds__(64, 2) void cluster_kernel(const float* __restrict__ x,
                                                        const f16x8* __restrict__ bfrag,
                                                        const float* __restrict__ c2,
                                                        float* __restrict__ out) {
    const int lane = threadIdx.x;      // 0..63
    const int r32  = lane & 31;
    const int g2   = lane >> 5;        // k-group
    const int row0 = blockIdx.x * 32;

    // A: lane reads row (row0 + r32), k = s*16 + g2*8 + v  (32B per step)
    const f32x4* ap = reinterpret_cast<const f32x4*>(
        x + (size_t)(row0 + r32) * DIM + g2 * 8);
    const f16x8* bp = bfrag + lane;

    f32x16 acc[8] = {};

    // ---- prologue: step 0 loads ----
    f32x4 aA = ap[0];
    f32x4 aB = ap[1];
    f16x8 b0[8];
#pragma unroll
    for (int t = 0; t < 8; ++t) b0[t] = bp[t * 64];

    float x2p = 0.0f;

#pragma unroll
    for (int s = 0; s < 16; ++s) {
        f32x4 nA, nB;
        f16x8 nb[8];
        if (s < 15) {
            nA = ap[(s + 1) * 4];
            nB = ap[(s + 1) * 4 + 1];
#pragma unroll
            for (int t = 0; t < 8; ++t) nb[t] = bp[((s + 1) * 8 + t) * 64];
        }
        // convert current A, accumulate sum-of-squares in fp32
        f16x8 ah;
        ah[0] = (_Float16)aA[0]; ah[1] = (_Float16)aA[1];
        ah[2] = (_Float16)aA[2]; ah[3] = (_Float16)aA[3];
        ah[4] = (_Float16)aB[0]; ah[5] = (_Float16)aB[1];
        ah[6] = (_Float16)aB[2]; ah[7] = (_Float16)aB[3];
        x2p += aA[0]*aA[0] + aA[1]*aA[1] + aA[2]*aA[2] + aA[3]*aA[3]
             + aB[0]*aB[0] + aB[1]*aB[1] + aB[2]*aB[2] + aB[3]*aB[3];

        __builtin_amdgcn_s_setprio(1);
#pragma unroll
        for (int t = 0; t < 8; ++t)
            acc[t] = __builtin_amdgcn_mfma_f32_32x32x16_f16(ah, b0[t], acc[t], 0, 0, 0);
        __builtin_amdgcn_s_setprio(0);

        if (s < 15) {
            aA = nA; aB = nB;
#pragma unroll
            for (int t = 0; t < 8; ++t) b0[t] = nb[t];
        }
    }

    // ---- x2: lane has half-row (its g2 k-range); combine across halves ----
    float x2full = x2p + __shfl_xor(x2p, 32, 64);   // x2[row r32], all lanes

    // c2 for this lane's columns (L2-hot)
    float c2v[8];
#pragma unroll
    for (int t = 0; t < 8; ++t) c2v[t] = c2[t * 32 + r32];

    // ---- epilogue: q = 1/(1+dist2), row-normalize, store ----
    // C/D layout (measured): col = lane&31, row = (reg&3) + 8*(reg>>2) + 4*(lane>>5)
#pragma unroll
    for (int j = 0; j < 16; ++j) {
        const int rowloc = (j & 3) + 8 * (j >> 2) + 4 * g2;
        float x2j = __shfl(x2full, rowloc, 64);
        float rs = 0.0f;
#pragma unroll
        for (int t = 0; t < 8; ++t) {
            float d2 = 1.0f + x2j + c2v[t] - 2.0f * acc[t][j];
            float q  = __builtin_amdgcn_rcpf(d2);
            acc[t][j] = q;
            rs += q;
        }
        // row lives in one 32-lane half (same g2): reduce masks 1..16
        rs += __shfl_xor(rs, 1, 64);
        rs += __shfl_xor(rs, 2, 64);
        rs += __shfl_xor(rs, 4, 64);
        rs += __shfl_xor(rs, 8, 64);
        rs += __shfl_xor(rs, 16, 64);
        float rn = __builtin_amdgcn_rcpf(rs);
        float* op = out + (size_t)(row0 + rowloc) * NCLUST + r32;
#pragma unroll
        for (int t = 0; t < 8; ++t) op[t * 32] = acc[t][j] * rn;
    }
}

extern "C" void kernel_launch(void* const* d_in, const int* in_sizes, int n_in,
                              void* d_out, int out_size, void* d_ws, size_t ws_size,
                              hipStream_t stream) {
    const float* x        = (const float*)d_in[0];
    const float* clusters = (const float*)d_in[1];
    float* out = (float*)d_out;

    _Float16* bfrag = (_Float16*)d_ws;                       // 128*64*16B = 128 KB
    float*    c2    = (float*)((char*)d_ws + 128 * 64 * 16); // 1 KB

    pre_kernel<<<384, 64, 0, stream>>>(clusters, bfrag, c2);

    int nrows = in_sizes[0] / DIM;          // 65536
    int grid  = nrows / 32;                 // 2048
    cluster_kernel<<<grid, 64, 0, stream>>>(x, (const f16x8*)bfrag, c2, out);
}